// Round 4
// baseline (97.142 us; speedup 1.0000x reference)
//
#include <hip/hip_runtime.h>
#include <math.h>

#define B_N 512
#define D_N 768
#define R_N 128
#define ALPHA 2.0f
#define BETA 50.0f
#define BASE 0.5f
#define EPS_M 0.1f
#define NB 8

typedef __attribute__((ext_vector_type(4))) float f32x4;
typedef __attribute__((ext_vector_type(8))) short s16x8;

static __device__ inline short f2bf(float f) {
    union { float f; unsigned u; } v; v.f = f;
    unsigned u = v.u;
    unsigned r = (u + 0x7FFFu + ((u >> 16) & 1u)) >> 16;  // RNE
    return (short)r;
}

// ---------------- Kernel 1: grouped matvec t[b] = M[re_id[b]] @ x[b] --------
// grid (128 relations, 24 tiles of 32 rows), block 256. Bucket scan fused.
__global__ __launch_bounds__(256, 3) void k_matvec(
    const float* __restrict__ transform, const float* __restrict__ cui0,
    const int* __restrict__ re_id, float* __restrict__ t_out) {
    int r = blockIdx.x;
    int tile = blockIdx.y * 32;
    int tid = threadIdx.x;

    __shared__ int mem_s[B_N];
    __shared__ int cnt_s;
    __shared__ float xs[NB][D_N];  // 24 KiB

    if (tid == 0) cnt_s = 0;
    __syncthreads();
    for (int i = tid; i < B_N; i += 256) {
        if (re_id[i] == r) {
            int k = atomicAdd(&cnt_s, 1);
            mem_s[k] = i;
        }
    }
    __syncthreads();
    int n = cnt_s;
    if (n == 0) return;

    int lane = tid & 63;
    int w = tid >> 6;
    int g = lane >> 4;    // which of 4 rows in a unit
    int l16 = lane & 15;  // k-slot within the row

    const float* Mbase = transform + (size_t)r * ((size_t)D_N * D_N);

    // rows owned by this wave: unit0 = tile + w*8 + g, unit1 = +4
    int i0 = tile + w * 8 + g;
    int i1 = i0 + 4;
    const float4* M0 = (const float4*)(Mbase + (size_t)i0 * D_N);
    const float4* M1 = (const float4*)(Mbase + (size_t)i1 * D_N);
    float4 m0[12], m1[12];
#pragma unroll
    for (int c = 0; c < 12; ++c) m0[c] = M0[l16 + 16 * c];
#pragma unroll
    for (int c = 0; c < 12; ++c) m1[c] = M1[l16 + 16 * c];

    for (int cs = 0; cs < n; cs += NB) {
        int nc = min(NB, n - cs);
        __syncthreads();  // previous chunk done before overwrite
        for (int idx = tid; idx < nc * 192; idx += 256) {
            int cb = idx / 192, pos = idx - cb * 192;
            int b = mem_s[cs + cb];
            ((float4*)xs[cb])[pos] = ((const float4*)(cui0 + (size_t)b * D_N))[pos];
        }
        __syncthreads();

        for (int cb = 0; cb < nc; ++cb) {
            const float4* xr = (const float4*)xs[cb];
            float a0 = 0.f, a1 = 0.f;
#pragma unroll
            for (int c = 0; c < 12; ++c) {
                float4 x = xr[l16 + 16 * c];
                a0 += m0[c].x * x.x + m0[c].y * x.y + m0[c].z * x.z + m0[c].w * x.w;
                a1 += m1[c].x * x.x + m1[c].y * x.y + m1[c].z * x.z + m1[c].w * x.w;
            }
            a0 += __shfl_xor(a0, 8, 64);
            a1 += __shfl_xor(a1, 8, 64);
            a0 += __shfl_xor(a0, 4, 64);
            a1 += __shfl_xor(a1, 4, 64);
            a0 += __shfl_xor(a0, 2, 64);
            a1 += __shfl_xor(a1, 2, 64);
            a0 += __shfl_xor(a0, 1, 64);
            a1 += __shfl_xor(a1, 1, 64);
            if (l16 == 0) {
                size_t ob = (size_t)mem_s[cs + cb] * D_N;
                t_out[ob + i0] = a0;
                t_out[ob + i1] = a1;
            }
        }
    }
}

// ---------------- Kernel 2: norms + bf16 MFMA gemm  mat = Tn @ Cn^T --------
// grid (8,8), block 256 (4 waves). Tile 64x64, wave sub-tile 32x32 (2x2 of
// 16x16x32 bf16 MFMA). LDS [64][72] short: 144B row stride -> 2-way banks.
__global__ __launch_bounds__(256) void k_gemm(
    const float* __restrict__ t_in, const float* __restrict__ cui1,
    float* __restrict__ mat, int* __restrict__ sync_cnt) {
    __shared__ short As[64][72];
    __shared__ short Bs[64][72];
    __shared__ float inv_s[128];
    __shared__ float nsum[128][2];

    int row0 = blockIdx.y * 64, col0 = blockIdx.x * 64;
    int tid = threadIdx.x;
    if (tid == 0 && blockIdx.x == 0 && blockIdx.y == 0) *sync_cnt = 0;

    // ---- norms pass: 128 rows (64 A, 64 B), 2 threads per row ----
    {
        int rr = tid >> 1, half = tid & 1;
        const float* src = (rr < 64) ? (t_in + (size_t)(row0 + rr) * D_N)
                                     : (cui1 + (size_t)(col0 + rr - 64) * D_N);
        const float4* s4 = (const float4*)src + half * 96;
        float ss = 0.f;
#pragma unroll 4
        for (int c = 0; c < 96; ++c) {
            float4 v = s4[c];
            ss += v.x * v.x + v.y * v.y + v.z * v.z + v.w * v.w;
        }
        nsum[rr][half] = ss;
    }
    __syncthreads();
    if (tid < 128) {
        float s = nsum[tid][0] + nsum[tid][1];
        inv_s[tid] = 1.0f / fmaxf(sqrtf(s), 1e-12f);
    }
    __syncthreads();

    int lane = tid & 63, w = tid >> 6;
    int wr = w >> 1, wc = w & 1;
    int l15 = lane & 15, lh = lane >> 4;
    int sr = tid >> 2, sc = tid & 3;  // staging: row sr, k-offset sc*16
    float inva = inv_s[sr];
    float invb = inv_s[64 + sr];

    f32x4 acc[2][2];
#pragma unroll
    for (int i = 0; i < 2; ++i)
#pragma unroll
        for (int j = 0; j < 2; ++j) acc[i][j] = (f32x4){0.f, 0.f, 0.f, 0.f};

    for (int k0 = 0; k0 < D_N; k0 += 64) {
        __syncthreads();
        {
            const float4* ap = (const float4*)(t_in + (size_t)(row0 + sr) * D_N + k0 + sc * 16);
            const float4* bp = (const float4*)(cui1 + (size_t)(col0 + sr) * D_N + k0 + sc * 16);
            float4 a0 = ap[0], a1 = ap[1], a2 = ap[2], a3 = ap[3];
            float4 b0 = bp[0], b1 = bp[1], b2 = bp[2], b3 = bp[3];
            s16x8 av0 = {f2bf(a0.x * inva), f2bf(a0.y * inva), f2bf(a0.z * inva), f2bf(a0.w * inva),
                         f2bf(a1.x * inva), f2bf(a1.y * inva), f2bf(a1.z * inva), f2bf(a1.w * inva)};
            s16x8 av1 = {f2bf(a2.x * inva), f2bf(a2.y * inva), f2bf(a2.z * inva), f2bf(a2.w * inva),
                         f2bf(a3.x * inva), f2bf(a3.y * inva), f2bf(a3.z * inva), f2bf(a3.w * inva)};
            s16x8 bv0 = {f2bf(b0.x * invb), f2bf(b0.y * invb), f2bf(b0.z * invb), f2bf(b0.w * invb),
                         f2bf(b1.x * invb), f2bf(b1.y * invb), f2bf(b1.z * invb), f2bf(b1.w * invb)};
            s16x8 bv1 = {f2bf(b2.x * invb), f2bf(b2.y * invb), f2bf(b2.z * invb), f2bf(b2.w * invb),
                         f2bf(b3.x * invb), f2bf(b3.y * invb), f2bf(b3.z * invb), f2bf(b3.w * invb)};
            *(s16x8*)&As[sr][sc * 16] = av0;
            *(s16x8*)&As[sr][sc * 16 + 8] = av1;
            *(s16x8*)&Bs[sr][sc * 16] = bv0;
            *(s16x8*)&Bs[sr][sc * 16 + 8] = bv1;
        }
        __syncthreads();
#pragma unroll
        for (int kc = 0; kc < 2; ++kc) {
            s16x8 af[2], bfr[2];
#pragma unroll
            for (int i = 0; i < 2; ++i) {
                af[i] = *(const s16x8*)&As[wr * 32 + i * 16 + l15][kc * 32 + lh * 8];
                bfr[i] = *(const s16x8*)&Bs[wc * 32 + i * 16 + l15][kc * 32 + lh * 8];
            }
#pragma unroll
            for (int i = 0; i < 2; ++i)
#pragma unroll
                for (int j = 0; j < 2; ++j)
                    acc[i][j] = __builtin_amdgcn_mfma_f32_16x16x32_bf16(
                        af[i], bfr[j], acc[i][j], 0, 0, 0);
        }
    }

    // epilogue: C/D layout col=lane&15, row=(lane>>4)*4+reg  [m89]
#pragma unroll
    for (int i = 0; i < 2; ++i)
#pragma unroll
        for (int j = 0; j < 2; ++j) {
            int grow = row0 + wr * 32 + i * 16 + lh * 4;
            int gcol = col0 + wc * 32 + j * 16 + l15;
#pragma unroll
            for (int p = 0; p < 4; ++p)
                mat[(size_t)(grow + p) * B_N + gcol] = acc[i][j][p];
        }
}

// ---------------- Kernel 3: miner + MS loss per row, fused mean ----------
__global__ __launch_bounds__(256) void k_loss(
    const float* __restrict__ mat, const int* __restrict__ lab,
    float* __restrict__ row_loss, int* __restrict__ sync_cnt,
    float* __restrict__ out) {
    int r = blockIdx.x;
    int tid = threadIdx.x;
    int lane = tid & 63, w = tid >> 6;
    __shared__ float tmp[4];
    __shared__ int is_last;
    int lr = lab[r];
    const float* mrow = mat + (size_t)r * B_N;

    float v0 = mrow[tid], v1 = mrow[tid + 256];
    bool m0 = (lab[tid] == lr), m1 = (lab[tid + 256] == lr);

    float mx = -INFINITY, mn = INFINITY;
    if (m0) mn = v0; else mx = v0;
    if (m1) mn = fminf(mn, v1); else mx = fmaxf(mx, v1);

#pragma unroll
    for (int off = 32; off > 0; off >>= 1) mx = fmaxf(mx, __shfl_xor(mx, off, 64));
    if (lane == 0) tmp[w] = mx;
    __syncthreads();
    float max_neg = fmaxf(fmaxf(tmp[0], tmp[1]), fmaxf(tmp[2], tmp[3]));
    __syncthreads();

#pragma unroll
    for (int off = 32; off > 0; off >>= 1) mn = fminf(mn, __shfl_xor(mn, off, 64));
    if (lane == 0) tmp[w] = mn;
    __syncthreads();
    float min_pos = fminf(fminf(tmp[0], tmp[1]), fminf(tmp[2], tmp[3]));
    __syncthreads();

    float psum = 0.f, nsum = 0.f;
    if (m0 && (v0 - EPS_M < max_neg)) psum += expf(ALPHA * (BASE - v0));
    if (!m0 && (v0 + EPS_M > min_pos)) nsum += expf(BETA * (v0 - BASE));
    if (m1 && (v1 - EPS_M < max_neg)) psum += expf(ALPHA * (BASE - v1));
    if (!m1 && (v1 + EPS_M > min_pos)) nsum += expf(BETA * (v1 - BASE));

#pragma unroll
    for (int off = 32; off > 0; off >>= 1) psum += __shfl_xor(psum, off, 64);
    if (lane == 0) tmp[w] = psum;
    __syncthreads();
    float ps = tmp[0] + tmp[1] + tmp[2] + tmp[3];
    __syncthreads();

#pragma unroll
    for (int off = 32; off > 0; off >>= 1) nsum += __shfl_xor(nsum, off, 64);
    if (lane == 0) tmp[w] = nsum;
    __syncthreads();
    float ns = tmp[0] + tmp[1] + tmp[2] + tmp[3];

    if (tid == 0) {
        row_loss[r] = (1.0f / ALPHA) * log1pf(ps) + (1.0f / BETA) * log1pf(ns);
        __threadfence();
        int prev = atomicAdd(sync_cnt, 1);
        is_last = (prev == B_N - 1) ? 1 : 0;
    }
    __syncthreads();
    if (is_last) {
        __threadfence();
        float v = row_loss[tid] + row_loss[tid + 256];
#pragma unroll
        for (int off = 32; off > 0; off >>= 1) v += __shfl_xor(v, off, 64);
        if (lane == 0) tmp[w] = v;
        __syncthreads();
        if (tid == 0)
            out[0] = (tmp[0] + tmp[1] + tmp[2] + tmp[3]) / (float)B_N;
    }
}

extern "C" void kernel_launch(void* const* d_in, const int* in_sizes, int n_in,
                              void* d_out, int out_size, void* d_ws, size_t ws_size,
                              hipStream_t stream) {
    const float* cui0      = (const float*)d_in[0];
    const float* cui1      = (const float*)d_in[1];
    const int*   re_id     = (const int*)d_in[2];
    const int*   lab1      = (const int*)d_in[4];
    const float* transform = (const float*)d_in[5];
    float* out = (float*)d_out;

    float* ws = (float*)d_ws;
    float* t        = ws;                          // 512*768
    float* mat      = t + (size_t)B_N * D_N;       // 512*512
    float* row_loss = mat + (size_t)B_N * B_N;     // 512
    int*   cnt      = (int*)(row_loss + B_N);      // 1

    hipLaunchKernelGGL(k_matvec, dim3(R_N, 24), dim3(256), 0, stream,
                       transform, cui0, re_id, t);
    hipLaunchKernelGGL(k_gemm, dim3(8, 8), dim3(256), 0, stream,
                       t, cui1, mat, cnt);
    hipLaunchKernelGGL(k_loss, dim3(B_N), dim3(256), 0, stream,
                       mat, lab1, row_loss, cnt, out);
}

// Round 5
// 88.873 us; speedup vs baseline: 1.0930x; 1.0930x over previous
//
#include <hip/hip_runtime.h>
#include <math.h>

#define B_N 512
#define D_N 768
#define R_N 128
#define ALPHA 2.0f
#define BETA 50.0f
#define BASE 0.5f
#define EPS_M 0.1f
#define NB 8
#define KCH 192  // 768 / 4 K-chunks for the gemm K-split

typedef __attribute__((ext_vector_type(4))) float f32x4;
typedef __attribute__((ext_vector_type(8))) short s16x8;

static __device__ inline short f2bf(float f) {
    union { float f; unsigned u; } v; v.f = f;
    unsigned u = v.u;
    unsigned r = (u + 0x7FFFu + ((u >> 16) & 1u)) >> 16;  // RNE
    return (short)r;
}

// ---------------- Kernel A: bucket rows by relation ----------------
__global__ void k_bucket(const int* __restrict__ re_id, int* __restrict__ cnt,
                         int* __restrict__ members) {
    int tid = threadIdx.x;  // 512 threads, 1 block
    if (tid < R_N) cnt[tid] = 0;
    __syncthreads();
    int r = re_id[tid];
    int k = atomicAdd(&cnt[r], 1);
    members[r * B_N + k] = tid;
}

// ---------------- Kernel B: grouped matvec t[b] = M[re_id[b]] @ x[b] --------
// grid (128 relations, 24 tiles of 32 rows), block 256.
// Each wave holds 2 units of 4 M-rows in registers (16 lanes per row).
__global__ __launch_bounds__(256, 3) void k_matvec(
    const float* __restrict__ transform, const float* __restrict__ cui0,
    const int* __restrict__ cnt, const int* __restrict__ members,
    float* __restrict__ t_out) {
    int r = blockIdx.x;
    int n = cnt[r];
    if (n == 0) return;
    int tile = blockIdx.y * 32;

    __shared__ float xs[NB][D_N];  // 24 KiB
    __shared__ int bs[NB];
    int tid = threadIdx.x;
    int lane = tid & 63;
    int w = tid >> 6;
    int g = lane >> 4;    // which of 4 rows in a unit
    int l16 = lane & 15;  // k-slot within the row

    const float* Mbase = transform + (size_t)r * ((size_t)D_N * D_N);
    const int* mrow = members + r * B_N;

    int i0 = tile + w * 8 + g;
    int i1 = i0 + 4;
    const float4* M0 = (const float4*)(Mbase + (size_t)i0 * D_N);
    const float4* M1 = (const float4*)(Mbase + (size_t)i1 * D_N);
    float4 m0[12], m1[12];
#pragma unroll
    for (int c = 0; c < 12; ++c) m0[c] = M0[l16 + 16 * c];
#pragma unroll
    for (int c = 0; c < 12; ++c) m1[c] = M1[l16 + 16 * c];

    for (int cs = 0; cs < n; cs += NB) {
        int nc = min(NB, n - cs);
        __syncthreads();  // previous chunk done before overwrite
        if (tid < nc) bs[tid] = mrow[cs + tid];
        for (int idx = tid; idx < nc * 192; idx += 256) {
            int cb = idx / 192, pos = idx - cb * 192;
            int b = mrow[cs + cb];
            ((float4*)xs[cb])[pos] = ((const float4*)(cui0 + (size_t)b * D_N))[pos];
        }
        __syncthreads();

        for (int cb = 0; cb < nc; ++cb) {
            const float4* xr = (const float4*)xs[cb];
            float a0 = 0.f, a1 = 0.f;
#pragma unroll
            for (int c = 0; c < 12; ++c) {
                float4 x = xr[l16 + 16 * c];
                a0 += m0[c].x * x.x + m0[c].y * x.y + m0[c].z * x.z + m0[c].w * x.w;
                a1 += m1[c].x * x.x + m1[c].y * x.y + m1[c].z * x.z + m1[c].w * x.w;
            }
            a0 += __shfl_xor(a0, 8, 64);
            a1 += __shfl_xor(a1, 8, 64);
            a0 += __shfl_xor(a0, 4, 64);
            a1 += __shfl_xor(a1, 4, 64);
            a0 += __shfl_xor(a0, 2, 64);
            a1 += __shfl_xor(a1, 2, 64);
            a0 += __shfl_xor(a0, 1, 64);
            a1 += __shfl_xor(a1, 1, 64);
            if (l16 == 0) {
                size_t ob = (size_t)bs[cb] * D_N;
                t_out[ob + i0] = a0;
                t_out[ob + i1] = a1;
            }
        }
    }
}

// ---------------- Kernel C: inverse row norms ----------------
__global__ __launch_bounds__(256) void k_norms(
    const float* __restrict__ t_in, const float* __restrict__ cui1,
    float* __restrict__ inv_t, float* __restrict__ inv_c) {
    int gw = blockIdx.x * 4 + (threadIdx.x >> 6);
    int lane = threadIdx.x & 63;
    const float* src = (gw < B_N) ? (t_in + (size_t)gw * D_N)
                                  : (cui1 + (size_t)(gw - B_N) * D_N);
    const float4* s4 = (const float4*)src;
    float s = 0.f;
#pragma unroll
    for (int c = 0; c < 3; ++c) {
        float4 v = s4[c * 64 + lane];
        s += v.x * v.x + v.y * v.y + v.z * v.z + v.w * v.w;
    }
#pragma unroll
    for (int off = 32; off > 0; off >>= 1) s += __shfl_down(s, off, 64);
    if (lane == 0) {
        float nrm = sqrtf(s);
        float inv = 1.0f / fmaxf(nrm, 1e-12f);
        if (gw < B_N) inv_t[gw] = inv;
        else inv_c[gw - B_N] = inv;
    }
}

// ---------------- Kernel D: bf16 MFMA partial GEMM, K split 4 ----------
// grid (8,8,4), block 256 (4 waves). Tile 64x64, wave 32x32 (2x2 of
// 16x16x32 bf16 MFMA). LDS [64][72] short rows -> 144B stride, 2-way banks.
__global__ __launch_bounds__(256) void k_gemm(
    const float* __restrict__ t_in, const float* __restrict__ cui1,
    const float* __restrict__ inv_t, const float* __restrict__ inv_c,
    float* __restrict__ part, int* __restrict__ sync_cnt) {
    __shared__ short As[64][72];
    __shared__ short Bs[64][72];

    int row0 = blockIdx.y * 64, col0 = blockIdx.x * 64;
    int kbase = blockIdx.z * KCH;
    int tid = threadIdx.x;
    if (tid == 0 && blockIdx.x == 0 && blockIdx.y == 0 && blockIdx.z == 0)
        *sync_cnt = 0;

    int lane = tid & 63, w = tid >> 6;
    int wr = w >> 1, wc = w & 1;
    int l15 = lane & 15, lh = lane >> 4;
    int sr = tid >> 2, sc = tid & 3;  // staging: row sr, k-offset sc*16
    float inva = inv_t[row0 + sr];
    float invb = inv_c[col0 + sr];

    f32x4 acc[2][2];
#pragma unroll
    for (int i = 0; i < 2; ++i)
#pragma unroll
        for (int j = 0; j < 2; ++j) acc[i][j] = (f32x4){0.f, 0.f, 0.f, 0.f};

    for (int ks = 0; ks < KCH; ks += 64) {
        int k0 = kbase + ks;
        __syncthreads();
        {
            const float4* ap = (const float4*)(t_in + (size_t)(row0 + sr) * D_N + k0 + sc * 16);
            const float4* bp = (const float4*)(cui1 + (size_t)(col0 + sr) * D_N + k0 + sc * 16);
            float4 a0 = ap[0], a1 = ap[1], a2 = ap[2], a3 = ap[3];
            float4 b0 = bp[0], b1 = bp[1], b2 = bp[2], b3 = bp[3];
            s16x8 av0 = {f2bf(a0.x * inva), f2bf(a0.y * inva), f2bf(a0.z * inva), f2bf(a0.w * inva),
                         f2bf(a1.x * inva), f2bf(a1.y * inva), f2bf(a1.z * inva), f2bf(a1.w * inva)};
            s16x8 av1 = {f2bf(a2.x * inva), f2bf(a2.y * inva), f2bf(a2.z * inva), f2bf(a2.w * inva),
                         f2bf(a3.x * inva), f2bf(a3.y * inva), f2bf(a3.z * inva), f2bf(a3.w * inva)};
            s16x8 bv0 = {f2bf(b0.x * invb), f2bf(b0.y * invb), f2bf(b0.z * invb), f2bf(b0.w * invb),
                         f2bf(b1.x * invb), f2bf(b1.y * invb), f2bf(b1.z * invb), f2bf(b1.w * invb)};
            s16x8 bv1 = {f2bf(b2.x * invb), f2bf(b2.y * invb), f2bf(b2.z * invb), f2bf(b2.w * invb),
                         f2bf(b3.x * invb), f2bf(b3.y * invb), f2bf(b3.z * invb), f2bf(b3.w * invb)};
            *(s16x8*)&As[sr][sc * 16] = av0;
            *(s16x8*)&As[sr][sc * 16 + 8] = av1;
            *(s16x8*)&Bs[sr][sc * 16] = bv0;
            *(s16x8*)&Bs[sr][sc * 16 + 8] = bv1;
        }
        __syncthreads();
#pragma unroll
        for (int kc = 0; kc < 2; ++kc) {
            s16x8 af[2], bfr[2];
#pragma unroll
            for (int i = 0; i < 2; ++i) {
                af[i] = *(const s16x8*)&As[wr * 32 + i * 16 + l15][kc * 32 + lh * 8];
                bfr[i] = *(const s16x8*)&Bs[wc * 32 + i * 16 + l15][kc * 32 + lh * 8];
            }
#pragma unroll
            for (int i = 0; i < 2; ++i)
#pragma unroll
                for (int j = 0; j < 2; ++j)
                    acc[i][j] = __builtin_amdgcn_mfma_f32_16x16x32_bf16(
                        af[i], bfr[j], acc[i][j], 0, 0, 0);
        }
    }

    // C/D layout col=lane&15, row=(lane>>4)*4+reg  [m89; HW-verified round 4]
    float* pz = part + (size_t)blockIdx.z * B_N * B_N;
#pragma unroll
    for (int i = 0; i < 2; ++i)
#pragma unroll
        for (int j = 0; j < 2; ++j) {
            int grow = row0 + wr * 32 + i * 16 + lh * 4;
            int gcol = col0 + wc * 32 + j * 16 + l15;
#pragma unroll
            for (int p = 0; p < 4; ++p)
                pz[(size_t)(grow + p) * B_N + gcol] = acc[i][j][p];
        }
}

// ---------------- Kernel E: miner + MS loss per row, fused mean ----------
__global__ __launch_bounds__(256) void k_loss(
    const float* __restrict__ part, const int* __restrict__ lab,
    float* __restrict__ row_loss, int* __restrict__ sync_cnt,
    float* __restrict__ out) {
    const int N2 = B_N * B_N;
    int r = blockIdx.x;
    int tid = threadIdx.x;
    int lane = tid & 63, w = tid >> 6;
    __shared__ float tmp[4];
    __shared__ int is_last;
    int lr = lab[r];
    size_t base = (size_t)r * B_N;

    float v0 = part[base + tid] + part[N2 + base + tid] +
               part[2 * N2 + base + tid] + part[3 * N2 + base + tid];
    int c1 = tid + 256;
    float v1 = part[base + c1] + part[N2 + base + c1] +
               part[2 * N2 + base + c1] + part[3 * N2 + base + c1];
    bool m0 = (lab[tid] == lr), m1 = (lab[c1] == lr);

    float mx = -INFINITY, mn = INFINITY;
    if (m0) mn = v0; else mx = v0;
    if (m1) mn = fminf(mn, v1); else mx = fmaxf(mx, v1);

#pragma unroll
    for (int off = 32; off > 0; off >>= 1) mx = fmaxf(mx, __shfl_xor(mx, off, 64));
    if (lane == 0) tmp[w] = mx;
    __syncthreads();
    float max_neg = fmaxf(fmaxf(tmp[0], tmp[1]), fmaxf(tmp[2], tmp[3]));
    __syncthreads();

#pragma unroll
    for (int off = 32; off > 0; off >>= 1) mn = fminf(mn, __shfl_xor(mn, off, 64));
    if (lane == 0) tmp[w] = mn;
    __syncthreads();
    float min_pos = fminf(fminf(tmp[0], tmp[1]), fminf(tmp[2], tmp[3]));
    __syncthreads();

    float psum = 0.f, nsum = 0.f;
    if (m0 && (v0 - EPS_M < max_neg)) psum += expf(ALPHA * (BASE - v0));
    if (!m0 && (v0 + EPS_M > min_pos)) nsum += expf(BETA * (v0 - BASE));
    if (m1 && (v1 - EPS_M < max_neg)) psum += expf(ALPHA * (BASE - v1));
    if (!m1 && (v1 + EPS_M > min_pos)) nsum += expf(BETA * (v1 - BASE));

#pragma unroll
    for (int off = 32; off > 0; off >>= 1) psum += __shfl_xor(psum, off, 64);
    if (lane == 0) tmp[w] = psum;
    __syncthreads();
    float ps = tmp[0] + tmp[1] + tmp[2] + tmp[3];
    __syncthreads();

#pragma unroll
    for (int off = 32; off > 0; off >>= 1) nsum += __shfl_xor(nsum, off, 64);
    if (lane == 0) tmp[w] = nsum;
    __syncthreads();
    float ns = tmp[0] + tmp[1] + tmp[2] + tmp[3];

    if (tid == 0) {
        row_loss[r] = (1.0f / ALPHA) * log1pf(ps) + (1.0f / BETA) * log1pf(ns);
        __threadfence();
        int prev = atomicAdd(sync_cnt, 1);
        is_last = (prev == B_N - 1) ? 1 : 0;
    }
    __syncthreads();
    if (is_last) {
        __threadfence();
        float v = row_loss[tid] + row_loss[tid + 256];
#pragma unroll
        for (int off = 32; off > 0; off >>= 1) v += __shfl_xor(v, off, 64);
        if (lane == 0) tmp[w] = v;
        __syncthreads();
        if (tid == 0)
            out[0] = (tmp[0] + tmp[1] + tmp[2] + tmp[3]) / (float)B_N;
    }
}

extern "C" void kernel_launch(void* const* d_in, const int* in_sizes, int n_in,
                              void* d_out, int out_size, void* d_ws, size_t ws_size,
                              hipStream_t stream) {
    const float* cui0      = (const float*)d_in[0];
    const float* cui1      = (const float*)d_in[1];
    const int*   re_id     = (const int*)d_in[2];
    const int*   lab1      = (const int*)d_in[4];
    const float* transform = (const float*)d_in[5];
    float* out = (float*)d_out;

    float* ws = (float*)d_ws;
    float* t        = ws;                          // 512*768
    float* inv_t    = t + (size_t)B_N * D_N;       // 512
    float* inv_c    = inv_t + B_N;                 // 512
    float* part     = inv_c + B_N;                 // 4*512*512
    float* row_loss = part + 4 * (size_t)B_N * B_N;  // 512
    int*   scnt     = (int*)(row_loss + B_N);      // 1
    int*   cnt      = (int*)(scnt + 4);            // 128
    int*   members  = cnt + R_N;                   // 128*512

    hipLaunchKernelGGL(k_bucket, dim3(1), dim3(B_N), 0, stream, re_id, cnt, members);
    hipLaunchKernelGGL(k_matvec, dim3(R_N, 24), dim3(256), 0, stream,
                       transform, cui0, cnt, members, t);
    hipLaunchKernelGGL(k_norms, dim3(256), dim3(256), 0, stream, t, cui1, inv_t, inv_c);
    hipLaunchKernelGGL(k_gemm, dim3(8, 8, 4), dim3(256), 0, stream,
                       t, cui1, inv_t, inv_c, part, scnt);
    hipLaunchKernelGGL(k_loss, dim3(B_N), dim3(256), 0, stream,
                       part, lab1, row_loss, scnt, out);
}

// Round 6
// 83.785 us; speedup vs baseline: 1.1594x; 1.0607x over previous
//
#include <hip/hip_runtime.h>
#include <math.h>

#define B_N 512
#define D_N 768
#define R_N 128
#define ALPHA 2.0f
#define BETA 50.0f
#define BASE 0.5f
#define EPS_M 0.1f
#define NB 8

typedef __attribute__((ext_vector_type(4))) float f32x4;
typedef __attribute__((ext_vector_type(8))) short s16x8;

static __device__ inline unsigned short f2bf(float f) {
    union { float f; unsigned u; } v; v.f = f;
    unsigned u = v.u;
    return (unsigned short)((u + 0x7FFFu + ((u >> 16) & 1u)) >> 16);  // RNE
}

// ---------------- Kernel 1: grouped matvec t[b] = M[re_id[b]] @ x[b] --------
// grid (128 relations, 24 tiles of 32 rows), block 256. Bucket scan fused,
// but M-row loads are issued BEFORE the scan so HBM latency overlaps it.
__global__ __launch_bounds__(256, 3) void k_matvec(
    const float* __restrict__ transform, const float* __restrict__ cui0,
    const int* __restrict__ re_id, float* __restrict__ t_out) {
    int r = blockIdx.x;
    int tile = blockIdx.y * 32;
    int tid = threadIdx.x;
    int lane = tid & 63;
    int w = tid >> 6;
    int g = lane >> 4;    // which of 4 rows in a unit
    int l16 = lane & 15;  // k-slot within the row

    const float* Mbase = transform + (size_t)r * ((size_t)D_N * D_N);
    int i0 = tile + w * 8 + g;
    int i1 = i0 + 4;
    const float4* M0 = (const float4*)(Mbase + (size_t)i0 * D_N);
    const float4* M1 = (const float4*)(Mbase + (size_t)i1 * D_N);
    float4 m0[12], m1[12];
#pragma unroll
    for (int c = 0; c < 12; ++c) m0[c] = M0[l16 + 16 * c];
#pragma unroll
    for (int c = 0; c < 12; ++c) m1[c] = M1[l16 + 16 * c];

    __shared__ int mem_s[B_N];
    __shared__ int cnt_s;
    __shared__ float xs[NB][D_N];  // 24 KiB

    if (tid == 0) cnt_s = 0;
    __syncthreads();
    {
        int a = re_id[tid], b = re_id[tid + 256];
        if (a == r) { int k = atomicAdd(&cnt_s, 1); mem_s[k] = tid; }
        if (b == r) { int k = atomicAdd(&cnt_s, 1); mem_s[k] = tid + 256; }
    }
    __syncthreads();
    int n = cnt_s;
    if (n == 0) return;

    for (int cs = 0; cs < n; cs += NB) {
        int nc = min(NB, n - cs);
        __syncthreads();  // previous chunk done before overwrite
        for (int idx = tid; idx < nc * 192; idx += 256) {
            int cb = idx / 192, pos = idx - cb * 192;
            int b = mem_s[cs + cb];
            ((float4*)xs[cb])[pos] = ((const float4*)(cui0 + (size_t)b * D_N))[pos];
        }
        __syncthreads();

        for (int cb = 0; cb < nc; ++cb) {
            const float4* xr = (const float4*)xs[cb];
            float a0 = 0.f, a1 = 0.f;
#pragma unroll
            for (int c = 0; c < 12; ++c) {
                float4 x = xr[l16 + 16 * c];
                a0 += m0[c].x * x.x + m0[c].y * x.y + m0[c].z * x.z + m0[c].w * x.w;
                a1 += m1[c].x * x.x + m1[c].y * x.y + m1[c].z * x.z + m1[c].w * x.w;
            }
            a0 += __shfl_xor(a0, 8, 64);
            a1 += __shfl_xor(a1, 8, 64);
            a0 += __shfl_xor(a0, 4, 64);
            a1 += __shfl_xor(a1, 4, 64);
            a0 += __shfl_xor(a0, 2, 64);
            a1 += __shfl_xor(a1, 2, 64);
            a0 += __shfl_xor(a0, 1, 64);
            a1 += __shfl_xor(a1, 1, 64);
            if (l16 == 0) {
                size_t ob = (size_t)mem_s[cs + cb] * D_N;
                t_out[ob + i0] = a0;
                t_out[ob + i1] = a1;
            }
        }
    }
}

// ---------------- Kernel 2: norms -> normalized bf16 copies ----------------
// grid 256, block 256 (4 waves); one wave per row, 1024 rows (512 t, 512 c).
__global__ __launch_bounds__(256) void k_normbf16(
    const float* __restrict__ t_in, const float* __restrict__ cui1,
    unsigned short* __restrict__ tn, unsigned short* __restrict__ cn,
    int* __restrict__ scnt) {
    if (blockIdx.x == 0 && threadIdx.x == 0) *scnt = 0;
    int gw = blockIdx.x * 4 + (threadIdx.x >> 6);
    int lane = threadIdx.x & 63;
    bool isA = gw < B_N;
    const float* src = isA ? (t_in + (size_t)gw * D_N)
                           : (cui1 + (size_t)(gw - B_N) * D_N);
    unsigned short* dst = isA ? (tn + (size_t)gw * D_N)
                              : (cn + (size_t)(gw - B_N) * D_N);
    const float4* s4 = (const float4*)src;
    float4 v[3];
    float ss = 0.f;
#pragma unroll
    for (int c = 0; c < 3; ++c) {
        v[c] = s4[c * 64 + lane];
        ss += v[c].x * v[c].x + v[c].y * v[c].y + v[c].z * v[c].z + v[c].w * v[c].w;
    }
#pragma unroll
    for (int off = 32; off > 0; off >>= 1) ss += __shfl_xor(ss, off, 64);
    float inv = 1.0f / fmaxf(sqrtf(ss), 1e-12f);
    ushort4* d4 = (ushort4*)dst;
#pragma unroll
    for (int c = 0; c < 3; ++c) {
        ushort4 o;
        o.x = f2bf(v[c].x * inv);
        o.y = f2bf(v[c].y * inv);
        o.z = f2bf(v[c].z * inv);
        o.w = f2bf(v[c].w * inv);
        d4[c * 64 + lane] = o;
    }
}

// ---------------- Kernel 3: LDS-free bf16 MFMA gemm  mat = Tn @ Cn^T -------
// grid (16,16), block 256 (4 waves). Each wave computes one 16x16 tile over
// full K=768 with fragments loaded straight from global bf16 (L2-resident).
// A/B frag layout: lane reads 8 contiguous bf16 at [row=l15][k=lh*8] (verified).
__global__ __launch_bounds__(256) void k_gemm(
    const unsigned short* __restrict__ tn, const unsigned short* __restrict__ cn,
    float* __restrict__ mat) {
    int tid = threadIdx.x;
    int lane = tid & 63, w = tid >> 6;
    int wr = w >> 1, wc = w & 1;
    int l15 = lane & 15, lh = lane >> 4;

    int arow = blockIdx.y * 32 + wr * 16 + l15;
    int bcol = blockIdx.x * 32 + wc * 16 + l15;
    const s16x8* ap = (const s16x8*)(tn + (size_t)arow * D_N);
    const s16x8* bp = (const s16x8*)(cn + (size_t)bcol * D_N);

    f32x4 acc0 = {0.f, 0.f, 0.f, 0.f};
    f32x4 acc1 = {0.f, 0.f, 0.f, 0.f};
#pragma unroll
    for (int ks = 0; ks < 24; ks += 2) {
        s16x8 a0 = ap[ks * 4 + lh];
        s16x8 b0 = bp[ks * 4 + lh];
        s16x8 a1 = ap[ks * 4 + 4 + lh];
        s16x8 b1 = bp[ks * 4 + 4 + lh];
        acc0 = __builtin_amdgcn_mfma_f32_16x16x32_bf16(a0, b0, acc0, 0, 0, 0);
        acc1 = __builtin_amdgcn_mfma_f32_16x16x32_bf16(a1, b1, acc1, 0, 0, 0);
    }

    // C/D layout col=lane&15, row=(lane>>4)*4+reg  [m89; HW-verified]
    int grow = blockIdx.y * 32 + wr * 16 + lh * 4;
    int gcol = bcol;
#pragma unroll
    for (int p = 0; p < 4; ++p)
        mat[(size_t)(grow + p) * B_N + gcol] = acc0[p] + acc1[p];
}

// ---------------- Kernel 4: miner + MS loss per row, fused mean ----------
__global__ __launch_bounds__(256) void k_loss(
    const float* __restrict__ mat, const int* __restrict__ lab,
    float* __restrict__ row_loss, int* __restrict__ sync_cnt,
    float* __restrict__ out) {
    int r = blockIdx.x;
    int tid = threadIdx.x;
    int lane = tid & 63, w = tid >> 6;
    __shared__ float tmp[4];
    __shared__ int is_last;
    int lr = lab[r];
    const float* mrow = mat + (size_t)r * B_N;

    float v0 = mrow[tid], v1 = mrow[tid + 256];
    bool m0 = (lab[tid] == lr), m1 = (lab[tid + 256] == lr);

    float mx = -INFINITY, mn = INFINITY;
    if (m0) mn = v0; else mx = v0;
    if (m1) mn = fminf(mn, v1); else mx = fmaxf(mx, v1);

#pragma unroll
    for (int off = 32; off > 0; off >>= 1) mx = fmaxf(mx, __shfl_xor(mx, off, 64));
    if (lane == 0) tmp[w] = mx;
    __syncthreads();
    float max_neg = fmaxf(fmaxf(tmp[0], tmp[1]), fmaxf(tmp[2], tmp[3]));
    __syncthreads();

#pragma unroll
    for (int off = 32; off > 0; off >>= 1) mn = fminf(mn, __shfl_xor(mn, off, 64));
    if (lane == 0) tmp[w] = mn;
    __syncthreads();
    float min_pos = fminf(fminf(tmp[0], tmp[1]), fminf(tmp[2], tmp[3]));
    __syncthreads();

    float psum = 0.f, nsum = 0.f;
    if (m0 && (v0 - EPS_M < max_neg)) psum += expf(ALPHA * (BASE - v0));
    if (!m0 && (v0 + EPS_M > min_pos)) nsum += expf(BETA * (v0 - BASE));
    if (m1 && (v1 - EPS_M < max_neg)) psum += expf(ALPHA * (BASE - v1));
    if (!m1 && (v1 + EPS_M > min_pos)) nsum += expf(BETA * (v1 - BASE));

#pragma unroll
    for (int off = 32; off > 0; off >>= 1) psum += __shfl_xor(psum, off, 64);
    if (lane == 0) tmp[w] = psum;
    __syncthreads();
    float ps = tmp[0] + tmp[1] + tmp[2] + tmp[3];
    __syncthreads();

#pragma unroll
    for (int off = 32; off > 0; off >>= 1) nsum += __shfl_xor(nsum, off, 64);
    if (lane == 0) tmp[w] = nsum;
    __syncthreads();
    float ns = tmp[0] + tmp[1] + tmp[2] + tmp[3];

    if (tid == 0) {
        row_loss[r] = (1.0f / ALPHA) * log1pf(ps) + (1.0f / BETA) * log1pf(ns);
        __threadfence();
        int prev = atomicAdd(sync_cnt, 1);
        is_last = (prev == B_N - 1) ? 1 : 0;
    }
    __syncthreads();
    if (is_last) {
        __threadfence();
        float v = row_loss[tid] + row_loss[tid + 256];
#pragma unroll
        for (int off = 32; off > 0; off >>= 1) v += __shfl_xor(v, off, 64);
        if (lane == 0) tmp[w] = v;
        __syncthreads();
        if (tid == 0)
            out[0] = (tmp[0] + tmp[1] + tmp[2] + tmp[3]) / (float)B_N;
    }
}

extern "C" void kernel_launch(void* const* d_in, const int* in_sizes, int n_in,
                              void* d_out, int out_size, void* d_ws, size_t ws_size,
                              hipStream_t stream) {
    const float* cui0      = (const float*)d_in[0];
    const float* cui1      = (const float*)d_in[1];
    const int*   re_id     = (const int*)d_in[2];
    const int*   lab1      = (const int*)d_in[4];
    const float* transform = (const float*)d_in[5];
    float* out = (float*)d_out;

    float* ws = (float*)d_ws;
    float* t        = ws;                           // 512*768 f32
    float* mat      = t + (size_t)B_N * D_N;        // 512*512 f32
    float* row_loss = mat + (size_t)B_N * B_N;      // 512
    int*   scnt     = (int*)(row_loss + B_N);       // 1 (+pad 4)
    unsigned short* tn = (unsigned short*)(row_loss + B_N + 4);  // 512*768 bf16
    unsigned short* cn = tn + (size_t)B_N * D_N;                 // 512*768 bf16

    hipLaunchKernelGGL(k_matvec, dim3(R_N, 24), dim3(256), 0, stream,
                       transform, cui0, re_id, t);
    hipLaunchKernelGGL(k_normbf16, dim3(256), dim3(256), 0, stream,
                       t, cui1, tn, cn, scnt);
    hipLaunchKernelGGL(k_gemm, dim3(16, 16), dim3(256), 0, stream,
                       tn, cn, mat);
    hipLaunchKernelGGL(k_loss, dim3(B_N), dim3(256), 0, stream,
                       mat, lab1, row_loss, scnt, out);
}